// Round 1
// 626.709 us; speedup vs baseline: 1.0326x; 1.0326x over previous
//
#include <hip/hip_runtime.h>
#include <hip/hip_bf16.h>

typedef __bf16 bf16x8 __attribute__((ext_vector_type(8)));
typedef float floatx4 __attribute__((ext_vector_type(4)));

#define LDK 72    // attn: P scratch stride (16 q rows x 64 k, +8 pad)

__device__ __forceinline__ unsigned short f2bf(float f) {
  unsigned u = __float_as_uint(f);
  u += 0x7fffu + ((u >> 16) & 1u);   // RNE; inputs finite
  return (unsigned short)(u >> 16);
}

__device__ __forceinline__ void async_copy16(const void* g, void* l) {
  __builtin_amdgcn_global_load_lds(
      (const __attribute__((address_space(1))) void*)g,
      (__attribute__((address_space(3))) void*)l, 16, 0, 0);
}

// ------------- elementwise fp32 -> bf16 (8 elems/thread) -------------
__global__ __launch_bounds__(256) void cvt_bf16(
    const float* __restrict__ in, unsigned short* __restrict__ out) {
  size_t i = ((size_t)blockIdx.x * 256 + threadIdx.x) * 8;
  float4 a0 = *(const float4*)&in[i];
  float4 a1 = *(const float4*)&in[i + 4];
  uint4 d;
  d.x = (unsigned)f2bf(a0.x) | ((unsigned)f2bf(a0.y) << 16);
  d.y = (unsigned)f2bf(a0.z) | ((unsigned)f2bf(a0.w) << 16);
  d.z = (unsigned)f2bf(a1.x) | ((unsigned)f2bf(a1.y) << 16);
  d.w = (unsigned)f2bf(a1.z) | ((unsigned)f2bf(a1.w) << 16);
  *(uint4*)(&out[i]) = d;
}

// ------------- convert+transpose: fp32 [R][Ccol] -> bf16 [Ccol][R] -------------
__global__ __launch_bounds__(256) void transpose_cvt(
    const float* __restrict__ in, unsigned short* __restrict__ out,
    int R, int Ccol) {
  __shared__ unsigned short tile[32][33];
  int c0 = blockIdx.x * 32, r0 = blockIdx.y * 32;
  int tx = threadIdx.x & 31, ty = threadIdx.x >> 5;  // 32 x 8
  #pragma unroll
  for (int i = 0; i < 32; i += 8)
    tile[ty + i][tx] = f2bf(in[(size_t)(r0 + ty + i) * Ccol + c0 + tx]);
  __syncthreads();
  #pragma unroll
  for (int i = 0; i < 32; i += 8)
    out[(size_t)(c0 + ty + i) * R + r0 + tx] = tile[tx][ty + i];
}

// ---- BT-GEMM mainloop (m97 structure): C[128x128] = A[m0..][K] * Bt[n0..][K]^T
// A,Bt bf16. Staging via global_load_lds width=16 into XOR-swizzled LDS
// (LDS slot (r,j) holds global 16B-chunk j^(r&7); rows 128B, no pad).
// Fragment reads land uniform 8 dwords/bank (conflict-free b128).
__device__ __forceinline__ void gemm_bt_mainloop(
    const unsigned short* __restrict__ A, const unsigned short* __restrict__ Bt,
    int K, int m0, int n0,
    unsigned short* As, unsigned short* Bs, floatx4 acc[4][4]) {
  const int t = threadIdx.x;
  const int lane = t & 63, w = t >> 6;
  const int wm = w >> 1, wn = w & 1;
  const int l15 = lane & 15, l4 = lane >> 4;
  const int lrow = lane >> 3, lchunk = lane & 7;   // staging: 8 rows x 8 chunks
  const int gch = lchunk ^ lrow;                   // source chunk for this lane
  const floatx4 zf = {0.f, 0.f, 0.f, 0.f};
  #pragma unroll
  for (int mi = 0; mi < 4; mi++)
    #pragma unroll
    for (int ni = 0; ni < 4; ni++) acc[mi][ni] = zf;

  for (int k0 = 0; k0 < K; k0 += 64) {
    __syncthreads();                 // prior iter's LDS reads done
    #pragma unroll
    for (int i = 0; i < 4; i++) {    // A: 16 regions of 8 rows; wave w -> w*4+i
      int ridx = w * 4 + i;
      int row = ridx * 8 + lrow;
      async_copy16(&A[(size_t)(m0 + row) * K + k0 + gch * 8], &As[ridx * 512]);
    }
    #pragma unroll
    for (int i = 0; i < 4; i++) {
      int ridx = w * 4 + i;
      int row = ridx * 8 + lrow;
      async_copy16(&Bt[(size_t)(n0 + row) * K + k0 + gch * 8], &Bs[ridx * 512]);
    }
    __syncthreads();                 // drains vmcnt -> staged data visible
    #pragma unroll
    for (int kk = 0; kk < 2; kk++) {
      bf16x8 af[4], bfr[4];
      #pragma unroll
      for (int mi = 0; mi < 4; mi++) {
        int row = wm * 64 + mi * 16 + l15;
        af[mi] = *(const bf16x8*)(&As[row * 64 + ((kk * 4 + l4) ^ (l15 & 7)) * 8]);
      }
      #pragma unroll
      for (int ni = 0; ni < 4; ni++) {
        int row = wn * 64 + ni * 16 + l15;
        bfr[ni] = *(const bf16x8*)(&Bs[row * 64 + ((kk * 4 + l4) ^ (l15 & 7)) * 8]);
      }
      #pragma unroll
      for (int mi = 0; mi < 4; mi++)
        #pragma unroll
        for (int ni = 0; ni < 4; ni++)
          acc[mi][ni] = __builtin_amdgcn_mfma_f32_16x16x32_bf16(
              af[mi], bfr[ni], acc[mi][ni], 0, 0, 0);
    }
  }
}

// ---- GEMM1: qkv = xb(bf16) @ w_qkvT(bf16) + b(fp32); Q,K [B,H,S,D], V^T [B,H,D,S]
__global__ __launch_bounds__(256, 3) void gemm_qkv(
    const unsigned short* __restrict__ X, const unsigned short* __restrict__ WT,
    const float* __restrict__ bias,
    unsigned short* __restrict__ Qo, unsigned short* __restrict__ Ko,
    unsigned short* __restrict__ Vto) {
  __shared__ unsigned short As[128 * 64];
  __shared__ unsigned short Bs[128 * 64];
  int n0 = blockIdx.x * 128, m0 = blockIdx.y * 128;
  floatx4 acc[4][4];
  gemm_bt_mainloop(X, WT, 2048, m0, n0, As, Bs, acc);

  const int t = threadIdx.x, lane = t & 63, w = t >> 6;
  const int wm = w >> 1, wn = w & 1;
  const int l15 = lane & 15, l4 = lane >> 4;
  int which = n0 >> 11;            // 0:Q 1:K 2:V  (2048-col boundaries)
  int h = (n0 & 2047) >> 7;        // one head per 128-col block
  int b = m0 >> 11;
  int s0 = m0 & 2047;
  float bv[4];
  #pragma unroll
  for (int ni = 0; ni < 4; ni++)
    bv[ni] = bias[n0 + wn * 64 + ni * 16 + l15];

  if (which < 2) {
    unsigned short* dst = (which == 0) ? Qo : Ko;
    size_t base = (size_t)(b * 16 + h) * 2048;
    #pragma unroll
    for (int mi = 0; mi < 4; mi++)
      #pragma unroll
      for (int ni = 0; ni < 4; ni++) {
        int d = wn * 64 + ni * 16 + l15;
        #pragma unroll
        for (int r = 0; r < 4; r++) {
          int srow = s0 + wm * 64 + mi * 16 + l4 * 4 + r;
          dst[(base + srow) * 128 + d] = f2bf(acc[mi][ni][r] + bv[ni]);
        }
      }
  } else {
    #pragma unroll
    for (int mi = 0; mi < 4; mi++)
      #pragma unroll
      for (int ni = 0; ni < 4; ni++) {
        int d = wn * 64 + ni * 16 + l15;
        int sr = s0 + wm * 64 + mi * 16 + l4 * 4;   // 4 consecutive s rows
        ushort4 v;
        v.x = f2bf(acc[mi][ni][0] + bv[ni]);
        v.y = f2bf(acc[mi][ni][1] + bv[ni]);
        v.z = f2bf(acc[mi][ni][2] + bv[ni]);
        v.w = f2bf(acc[mi][ni][3] + bv[ni]);
        *(ushort4*)(&Vto[((size_t)(b * 16 + h) * 128 + d) * 2048 + sr]) = v;
      }
  }
}

// ---- attn staging: K tile [64][128] + V^T tile [128][64] via global_load_lds,
// linear LDS dest, XOR-swizzled global source (slot (r,j) holds chunk j^(r&7)).
// 16 loads of 1024B per tile per operand, 4 per wave.
__device__ __forceinline__ void attn_stage(
    const unsigned short* __restrict__ Kb, const unsigned short* __restrict__ Vb,
    __bf16* Ksel, __bf16* Vsel, int k0, int lane, int w) {
  const int krow_in = lane >> 4, kch = lane & 15;  // K: 4 rows x 16 chunks / load
  const int vrow_in = lane >> 3, vch = lane & 7;   // V: 8 rows x 8 chunks / load
  #pragma unroll
  for (int u = 0; u < 4; u++) {
    int uk = w * 4 + u;
    int row = uk * 4 + krow_in;                    // row & 7 covers full 0..7
    int sch = kch ^ (row & 7);
    async_copy16(&Kb[(size_t)(k0 + row) * 128 + sch * 8], Ksel + uk * 512);
  }
  #pragma unroll
  for (int u = 0; u < 4; u++) {
    int uv = w * 4 + u;
    int row = uv * 8 + vrow_in;                    // row & 7 == vrow_in
    int sch = vch ^ vrow_in;
    async_copy16(&Vb[(size_t)row * 2048 + k0 + sch * 8], Vsel + uv * 512);
  }
}

// ---- flash attention: Q,K [B,H,S,D], V^T [B,H,D,S] (bf16) -> Y [B,S,C] (bf16)
// 2-phase async pipeline: double-buffered K/V staged by global_load_lds;
// prefetch tile kt+1 issued before computing kt; ONE __syncthreads per tile
// (its vmcnt(0) drain retires the prefetch). P in separate per-wave LDS.
// LDS 73 KB -> 2 blocks/CU.
__global__ __launch_bounds__(256, 2) void attn(
    const unsigned short* __restrict__ Qg, const unsigned short* __restrict__ Kg,
    const unsigned short* __restrict__ Vtg, unsigned short* __restrict__ Yg) {
  const int S = 2048, Dh = 128;
  const float c1 = 0.08838834764831845f * 1.4426950408889634f;  // scale*log2e
  const float NEG_BIG = -3.0e38f;
  __shared__ __bf16 Ks[2][64 * 128];   // K tile, swizzled chunks, no pad
  __shared__ __bf16 Vs[2][128 * 64];   // V^T tile, swizzled chunks, no pad
  __shared__ __bf16 Pl[4][16 * LDK];   // per-wave P [16 q][64 k], stride 72

  // XCD-aware remap: physical block n lands on XCD n%8; give each XCD a
  // contiguous run of (b,h) so K/V panels stay L2-resident. 1024 % 8 == 0.
  int wg = blockIdx.x;
  int lg = (wg & 7) * 128 + (wg >> 3);
  int qtp = lg & 15;
  int bh = lg >> 4;
  const int t = threadIdx.x, lane = t & 63, w = t >> 6;
  const int l15 = lane & 15, l4 = lane >> 4;
  const unsigned short* Qb = Qg + (size_t)bh * S * Dh;
  const unsigned short* Kb = Kg + (size_t)bh * S * Dh;
  const unsigned short* Vb = Vtg + (size_t)bh * Dh * S;
  __bf16* Pw = Pl[w];
  int b = bh >> 4, h = bh & 15;
  const floatx4 zf = {0.f, 0.f, 0.f, 0.f};

  #pragma unroll 1
  for (int half = 0; half < 2; half++) {
    int qt = half ? qtp : (31 - qtp);   // pair long+short halves: equal work/block
    int q0 = qt * 64;
    int qrow_base = q0 + w * 16;
    bf16x8 qf[4];
    #pragma unroll
    for (int kk = 0; kk < 4; kk++)
      qf[kk] = *(const bf16x8*)(
          &Qb[(size_t)(qrow_base + l15) * Dh + kk * 32 + l4 * 8]);
    floatx4 accO[8];
    #pragma unroll
    for (int nd = 0; nd < 8; nd++) accO[nd] = zf;
    float mst[4], lst[4];
    #pragma unroll
    for (int r = 0; r < 4; r++) { mst[r] = NEG_BIG; lst[r] = 0.f; }

    int ntiles = qt + 1;
    int cur = 0;
    attn_stage(Kb, Vb, Ks[0], Vs[0], 0, lane, w);
    __syncthreads();                    // vmcnt(0) drain + barrier: tile 0 ready

    #pragma unroll 1
    for (int kt = 0; kt < ntiles; kt++) {
      if (kt + 1 < ntiles)              // async prefetch into the other buffer
        attn_stage(Kb, Vb, Ks[cur ^ 1], Vs[cur ^ 1], (kt + 1) * 64, lane, w);

      const __bf16* Kcur = Ks[cur];
      const __bf16* Vcur = Vs[cur];
      floatx4 sc[4];
      #pragma unroll
      for (int ni = 0; ni < 4; ni++) sc[ni] = zf;
      #pragma unroll
      for (int kk = 0; kk < 4; kk++) {  // QK^T over D=128
        bf16x8 kf[4];
        #pragma unroll
        for (int ni = 0; ni < 4; ni++) {
          int row = ni * 16 + l15;
          kf[ni] = *(const bf16x8*)(
              &Kcur[row * 128 + (((kk * 4 + l4) ^ (l15 & 7)) << 3)]);
        }
        #pragma unroll
        for (int ni = 0; ni < 4; ni++)
          sc[ni] = __builtin_amdgcn_mfma_f32_16x16x32_bf16(qf[kk], kf[ni], sc[ni], 0, 0, 0);
      }

      if (kt == qt) {
        #pragma unroll
        for (int ni = 0; ni < 4; ni++)
          #pragma unroll
          for (int r = 0; r < 4; r++)
            if (ni * 16 + l15 > w * 16 + l4 * 4 + r) sc[ni][r] = NEG_BIG;
      }
      float mt[4];
      #pragma unroll
      for (int r = 0; r < 4; r++)
        mt[r] = fmaxf(fmaxf(sc[0][r], sc[1][r]), fmaxf(sc[2][r], sc[3][r]));
      #pragma unroll
      for (int off = 1; off < 16; off <<= 1)
        #pragma unroll
        for (int r = 0; r < 4; r++)
          mt[r] = fmaxf(mt[r], __shfl_xor(mt[r], off, 64));
      float alpha[4], rs[4];
      #pragma unroll
      for (int r = 0; r < 4; r++) {
        float mnew = fmaxf(mst[r], mt[r]);
        alpha[r] = exp2f((mst[r] - mnew) * c1);
        mst[r] = mnew;
        rs[r] = 0.f;
      }
      #pragma unroll
      for (int ni = 0; ni < 4; ni++)
        #pragma unroll
        for (int r = 0; r < 4; r++) {
          float p = exp2f((sc[ni][r] - mst[r]) * c1);
          rs[r] += p;
          Pw[(l4 * 4 + r) * LDK + ni * 16 + l15] = __builtin_bit_cast(__bf16, f2bf(p));
        }
      #pragma unroll
      for (int off = 1; off < 16; off <<= 1)
        #pragma unroll
        for (int r = 0; r < 4; r++)
          rs[r] += __shfl_xor(rs[r], off, 64);
      #pragma unroll
      for (int r = 0; r < 4; r++)
        lst[r] = lst[r] * alpha[r] + rs[r];
      #pragma unroll
      for (int nd = 0; nd < 8; nd++)
        #pragma unroll
        for (int r = 0; r < 4; r++) accO[nd][r] *= alpha[r];
      #pragma unroll
      for (int kk = 0; kk < 2; kk++) {
        bf16x8 pf = *(const bf16x8*)(&Pw[l15 * LDK + kk * 32 + l4 * 8]);
        #pragma unroll
        for (int nd = 0; nd < 8; nd++) {
          int row = nd * 16 + l15;
          bf16x8 vf = *(const bf16x8*)(
              &Vcur[row * 64 + (((kk * 4 + l4) ^ (l15 & 7)) << 3)]);
          accO[nd] = __builtin_amdgcn_mfma_f32_16x16x32_bf16(pf, vf, accO[nd], 0, 0, 0);
        }
      }
      __syncthreads();   // vmcnt(0): prefetch landed; all reads of cur done
      cur ^= 1;
    }
    #pragma unroll
    for (int r = 0; r < 4; r++) {
      float inv = 1.0f / lst[r];
      int srow = qrow_base + l4 * 4 + r;
      size_t rowbase = ((size_t)(b * 2048 + srow)) * 2048 + h * 128;
      #pragma unroll
      for (int nd = 0; nd < 8; nd++)
        Yg[rowbase + nd * 16 + l15] = f2bf(accO[nd][r] * inv);
    }
  }
}

// ---- GEMM2: out(fp32) = y(bf16) @ w_projT(bf16) + b_proj(fp32)
__global__ __launch_bounds__(256, 3) void gemm_proj(
    const unsigned short* __restrict__ Yin, const unsigned short* __restrict__ WT,
    const float* __restrict__ bias, float* __restrict__ Og) {
  __shared__ unsigned short As[128 * 64];
  __shared__ unsigned short Bs[128 * 64];
  int n0 = blockIdx.x * 128, m0 = blockIdx.y * 128;
  floatx4 acc[4][4];
  gemm_bt_mainloop(Yin, WT, 2048, m0, n0, As, Bs, acc);

  const int t = threadIdx.x, lane = t & 63, w = t >> 6;
  const int wm = w >> 1, wn = w & 1;
  const int l15 = lane & 15, l4 = lane >> 4;
  float bv[4];
  #pragma unroll
  for (int ni = 0; ni < 4; ni++)
    bv[ni] = bias[n0 + wn * 64 + ni * 16 + l15];
  #pragma unroll
  for (int mi = 0; mi < 4; mi++)
    #pragma unroll
    for (int ni = 0; ni < 4; ni++)
      #pragma unroll
      for (int r = 0; r < 4; r++)
        Og[(size_t)(m0 + wm * 64 + mi * 16 + l4 * 4 + r) * 2048 +
           n0 + wn * 64 + ni * 16 + l15] = acc[mi][ni][r] + bv[ni];
}

extern "C" void kernel_launch(void* const* d_in, const int* in_sizes, int n_in,
                              void* d_out, int out_size, void* d_ws, size_t ws_size,
                              hipStream_t stream) {
  const float* x      = (const float*)d_in[0]; // [4,2048,2048] fp32
  const float* w_qkv  = (const float*)d_in[1]; // [2048,6144] fp32
  const float* b_qkv  = (const float*)d_in[2]; // [6144] fp32
  const float* w_proj = (const float*)d_in[3]; // [2048,2048] fp32
  const float* b_proj = (const float*)d_in[4]; // [2048] fp32
  float* out = (float*)d_out;                  // [4,2048,2048] fp32 (64 MiB)
  char* ws = (char*)d_ws;

  // d_out doubles as mid-pipeline scratch (fully overwritten by gemm_proj):
  //   Q bf16 at d_out[0,32M), K bf16 at d_out[32M,64M)
  // ws (88 MiB peak), lifetime-shared:
  //   [0,32M):  Vt bf16 [B,H,D,S]
  //   [32,64M): Xbf bf16 (cvt_x -> gemm_qkv), then Y bf16 (attn -> gemm_proj)
  //   [64,88M): WqT bf16 [6144,2048], later WpT bf16 [2048,2048]
  unsigned short* Q   = (unsigned short*)d_out;
  unsigned short* Kt  = (unsigned short*)((char*)d_out + 33554432);
  unsigned short* Vt  = (unsigned short*)(ws);
  unsigned short* Xbf = (unsigned short*)(ws + 33554432);
  unsigned short* Y   = (unsigned short*)(ws + 33554432);
  unsigned short* WqT = (unsigned short*)(ws + 67108864);
  unsigned short* WpT = (unsigned short*)(ws + 67108864);

  cvt_bf16<<<dim3(8192), 256, 0, stream>>>(x, Xbf);                    // 16M elems
  transpose_cvt<<<dim3(192, 64), 256, 0, stream>>>(w_qkv, WqT, 2048, 6144);
  gemm_qkv<<<dim3(48, 64), 256, 0, stream>>>(Xbf, WqT, b_qkv, Q, Kt, Vt);
  attn<<<dim3(1024), 256, 0, stream>>>(Q, Kt, Vt, Y);
  transpose_cvt<<<dim3(64, 64), 256, 0, stream>>>(w_proj, WpT, 2048, 2048);
  gemm_proj<<<dim3(16, 64), 256, 0, stream>>>(Y, WpT, b_proj, out);
}

// Round 2
// 565.165 us; speedup vs baseline: 1.1450x; 1.1089x over previous
//
#include <hip/hip_runtime.h>
#include <hip/hip_bf16.h>

typedef __bf16 bf16x8 __attribute__((ext_vector_type(8)));
typedef float floatx4 __attribute__((ext_vector_type(4)));

__device__ __forceinline__ unsigned short f2bf(float f) {
  unsigned u = __float_as_uint(f);
  u += 0x7fffu + ((u >> 16) & 1u);   // RNE; inputs finite
  return (unsigned short)(u >> 16);
}

__device__ __forceinline__ unsigned cvt_pk_bf16(float lo, float hi) {
  unsigned r;
  asm("v_cvt_pk_bf16_f32 %0, %1, %2" : "=v"(r) : "v"(lo), "v"(hi));
  return r;   // r.lo16 = bf16(lo), r.hi16 = bf16(hi)
}

__device__ __forceinline__ void async_copy16(const void* g, void* l) {
  __builtin_amdgcn_global_load_lds(
      (const __attribute__((address_space(1))) void*)g,
      (__attribute__((address_space(3))) void*)l, 16, 0, 0);
}

// ------------- elementwise fp32 -> bf16 (8 elems/thread) -------------
__global__ __launch_bounds__(256) void cvt_bf16(
    const float* __restrict__ in, unsigned short* __restrict__ out) {
  size_t i = ((size_t)blockIdx.x * 256 + threadIdx.x) * 8;
  float4 a0 = *(const float4*)&in[i];
  float4 a1 = *(const float4*)&in[i + 4];
  uint4 d;
  d.x = (unsigned)f2bf(a0.x) | ((unsigned)f2bf(a0.y) << 16);
  d.y = (unsigned)f2bf(a0.z) | ((unsigned)f2bf(a0.w) << 16);
  d.z = (unsigned)f2bf(a1.x) | ((unsigned)f2bf(a1.y) << 16);
  d.w = (unsigned)f2bf(a1.z) | ((unsigned)f2bf(a1.w) << 16);
  *(uint4*)(&out[i]) = d;
}

// ------------- convert+transpose: fp32 [R][Ccol] -> bf16 [Ccol][R] -------------
__global__ __launch_bounds__(256) void transpose_cvt(
    const float* __restrict__ in, unsigned short* __restrict__ out,
    int R, int Ccol) {
  __shared__ unsigned short tile[32][33];
  int c0 = blockIdx.x * 32, r0 = blockIdx.y * 32;
  int tx = threadIdx.x & 31, ty = threadIdx.x >> 5;  // 32 x 8
  #pragma unroll
  for (int i = 0; i < 32; i += 8)
    tile[ty + i][tx] = f2bf(in[(size_t)(r0 + ty + i) * Ccol + c0 + tx]);
  __syncthreads();
  #pragma unroll
  for (int i = 0; i < 32; i += 8)
    out[(size_t)(c0 + ty + i) * R + r0 + tx] = tile[tx][ty + i];
}

// ---- BT-GEMM mainloop (m97 structure): C[128x128] = A[m0..][K] * Bt[n0..][K]^T
__device__ __forceinline__ void gemm_bt_mainloop(
    const unsigned short* __restrict__ A, const unsigned short* __restrict__ Bt,
    int K, int m0, int n0,
    unsigned short* As, unsigned short* Bs, floatx4 acc[4][4]) {
  const int t = threadIdx.x;
  const int lane = t & 63, w = t >> 6;
  const int wm = w >> 1, wn = w & 1;
  const int l15 = lane & 15, l4 = lane >> 4;
  const int lrow = lane >> 3, lchunk = lane & 7;   // staging: 8 rows x 8 chunks
  const int gch = lchunk ^ lrow;                   // source chunk for this lane
  const floatx4 zf = {0.f, 0.f, 0.f, 0.f};
  #pragma unroll
  for (int mi = 0; mi < 4; mi++)
    #pragma unroll
    for (int ni = 0; ni < 4; ni++) acc[mi][ni] = zf;

  for (int k0 = 0; k0 < K; k0 += 64) {
    __syncthreads();                 // prior iter's LDS reads done
    #pragma unroll
    for (int i = 0; i < 4; i++) {    // A: 16 regions of 8 rows; wave w -> w*4+i
      int ridx = w * 4 + i;
      int row = ridx * 8 + lrow;
      async_copy16(&A[(size_t)(m0 + row) * K + k0 + gch * 8], &As[ridx * 512]);
    }
    #pragma unroll
    for (int i = 0; i < 4; i++) {
      int ridx = w * 4 + i;
      int row = ridx * 8 + lrow;
      async_copy16(&Bt[(size_t)(n0 + row) * K + k0 + gch * 8], &Bs[ridx * 512]);
    }
    __syncthreads();                 // drains vmcnt -> staged data visible
    #pragma unroll
    for (int kk = 0; kk < 2; kk++) {
      bf16x8 af[4], bfr[4];
      #pragma unroll
      for (int mi = 0; mi < 4; mi++) {
        int row = wm * 64 + mi * 16 + l15;
        af[mi] = *(const bf16x8*)(&As[row * 64 + ((kk * 4 + l4) ^ (l15 & 7)) * 8]);
      }
      #pragma unroll
      for (int ni = 0; ni < 4; ni++) {
        int row = wn * 64 + ni * 16 + l15;
        bfr[ni] = *(const bf16x8*)(&Bs[row * 64 + ((kk * 4 + l4) ^ (l15 & 7)) * 8]);
      }
      #pragma unroll
      for (int mi = 0; mi < 4; mi++)
        #pragma unroll
        for (int ni = 0; ni < 4; ni++)
          acc[mi][ni] = __builtin_amdgcn_mfma_f32_16x16x32_bf16(
              af[mi], bfr[ni], acc[mi][ni], 0, 0, 0);
    }
  }
}

// ---- GEMM1: qkv = xb(bf16) @ w_qkvT(bf16) + b(fp32); Q,K [B,H,S,D], V^T [B,H,D,S]
__global__ __launch_bounds__(256, 3) void gemm_qkv(
    const unsigned short* __restrict__ X, const unsigned short* __restrict__ WT,
    const float* __restrict__ bias,
    unsigned short* __restrict__ Qo, unsigned short* __restrict__ Ko,
    unsigned short* __restrict__ Vto) {
  __shared__ unsigned short As[128 * 64];
  __shared__ unsigned short Bs[128 * 64];
  int n0 = blockIdx.x * 128, m0 = blockIdx.y * 128;
  floatx4 acc[4][4];
  gemm_bt_mainloop(X, WT, 2048, m0, n0, As, Bs, acc);

  const int t = threadIdx.x, lane = t & 63, w = t >> 6;
  const int wm = w >> 1, wn = w & 1;
  const int l15 = lane & 15, l4 = lane >> 4;
  int which = n0 >> 11;            // 0:Q 1:K 2:V  (2048-col boundaries)
  int h = (n0 & 2047) >> 7;        // one head per 128-col block
  int b = m0 >> 11;
  int s0 = m0 & 2047;
  float bv[4];
  #pragma unroll
  for (int ni = 0; ni < 4; ni++)
    bv[ni] = bias[n0 + wn * 64 + ni * 16 + l15];

  if (which < 2) {
    unsigned short* dst = (which == 0) ? Qo : Ko;
    size_t base = (size_t)(b * 16 + h) * 2048;
    #pragma unroll
    for (int mi = 0; mi < 4; mi++)
      #pragma unroll
      for (int ni = 0; ni < 4; ni++) {
        int d = wn * 64 + ni * 16 + l15;
        #pragma unroll
        for (int r = 0; r < 4; r++) {
          int srow = s0 + wm * 64 + mi * 16 + l4 * 4 + r;
          dst[(base + srow) * 128 + d] = f2bf(acc[mi][ni][r] + bv[ni]);
        }
      }
  } else {
    #pragma unroll
    for (int mi = 0; mi < 4; mi++)
      #pragma unroll
      for (int ni = 0; ni < 4; ni++) {
        int d = wn * 64 + ni * 16 + l15;
        int sr = s0 + wm * 64 + mi * 16 + l4 * 4;   // 4 consecutive s rows
        ushort4 v;
        v.x = f2bf(acc[mi][ni][0] + bv[ni]);
        v.y = f2bf(acc[mi][ni][1] + bv[ni]);
        v.z = f2bf(acc[mi][ni][2] + bv[ni]);
        v.w = f2bf(acc[mi][ni][3] + bv[ni]);
        *(ushort4*)(&Vto[((size_t)(b * 16 + h) * 128 + d) * 2048 + sr]) = v;
      }
  }
}

// ---- attn staging (512 threads): K tile [64][128] + V^T tile [128][64] via
// global_load_lds width=16; linear LDS dest, XOR-swizzled global source
// (slot (r,c) holds 16B-chunk c^(r&7)). 16 loads per operand, 2 per wave.
__device__ __forceinline__ void attn_stage(
    const unsigned short* __restrict__ Kb, const unsigned short* __restrict__ Vb,
    __bf16* Ksel, __bf16* Vsel, int k0, int lane, int w) {
  const int krow_in = lane >> 4, kch = lane & 15;  // K: 4 rows x 16 chunks / load
  const int vrow_in = lane >> 3, vch = lane & 7;   // V: 8 rows x 8 chunks / load
  #pragma unroll
  for (int u = 0; u < 2; u++) {
    int uk = w * 2 + u;
    int row = uk * 4 + krow_in;
    int sch = kch ^ (row & 7);
    async_copy16(&Kb[(size_t)(k0 + row) * 128 + sch * 8], Ksel + uk * 512);
  }
  #pragma unroll
  for (int u = 0; u < 2; u++) {
    int uv = w * 2 + u;
    int row = uv * 8 + vrow_in;                    // row & 7 == vrow_in
    int sch = vch ^ vrow_in;
    async_copy16(&Vb[(size_t)row * 2048 + k0 + sch * 8], Vsel + uv * 512);
  }
}

// ---- flash attention, 8-wave blocks, swapped-QK^T in-register softmax.
// Q,K [B,H,S,D], V^T [B,H,D,S] (bf16) -> Y [B,S,C] (bf16).
// Per wave: 16 q rows. QK^T computed as mfma(K,Q) so each lane owns ONE
// q-row (q=lane&15, keys (lane>>4)*4+r+16*ni): softmax reduce = in-lane
// + 2 shfl_xor; m/l state scalar per lane. P packed via v_cvt_pk_bf16_f32
// into per-wave swizzled LDS (4 b64 writes), read back as PV A-fragment
// (2 b128). Defer-max (THR=8) skips accO rescale on no-growth tiles.
// K/V double-buffered via global_load_lds, 1 barrier/tile. 80KB LDS ->
// 2 blocks/CU = 4 waves/SIMD.
__global__ __launch_bounds__(512, 4) void attn(
    const unsigned short* __restrict__ Qg, const unsigned short* __restrict__ Kg,
    const unsigned short* __restrict__ Vtg, unsigned short* __restrict__ Yg) {
  const int S = 2048, Dh = 128;
  const float c1 = 0.08838834764831845f * 1.4426950408889634f;  // scale*log2e
  const float NEG_BIG = -3.0e38f;
  __shared__ __bf16 Ks[2][64 * 128];   // K tile, swizzled chunks, no pad
  __shared__ __bf16 Vs[2][128 * 64];   // V^T tile, swizzled chunks, no pad
  __shared__ __bf16 Ps[8][16 * 64];    // per-wave P [16 q][64 k], swizzled

  // XCD-aware remap: physical block n -> XCD n%8; contiguous (b,h) per XCD.
  int wg = blockIdx.x;
  int lg = (wg & 7) * 64 + (wg >> 3);  // 512 blocks, 512%8==0 (bijective)
  int qtp = lg & 7;                    // 8 q-pair slots
  int bh = lg >> 3;
  const int t = threadIdx.x, lane = t & 63, w = t >> 6;
  const int l15 = lane & 15, l4 = lane >> 4;
  const unsigned short* Qb = Qg + (size_t)bh * S * Dh;
  const unsigned short* Kb = Kg + (size_t)bh * S * Dh;
  const unsigned short* Vb = Vtg + (size_t)bh * Dh * S;
  __bf16* Pw = Ps[w];
  int b = bh >> 4, h = bh & 15;
  const floatx4 zf = {0.f, 0.f, 0.f, 0.f};

  #pragma unroll 1
  for (int half = 0; half < 2; half++) {
    int jq = half ? qtp : (15 - qtp);  // pair long+short: 34 tiles per block
    int qb0 = jq * 128;
    int qrow_base = qb0 + w * 16;
    bf16x8 qf[4];
    #pragma unroll
    for (int kk = 0; kk < 4; kk++)
      qf[kk] = *(const bf16x8*)(
          &Qb[(size_t)(qrow_base + l15) * Dh + kk * 32 + l4 * 8]);
    floatx4 accO[8];
    #pragma unroll
    for (int nd = 0; nd < 8; nd++) accO[nd] = zf;
    float mst = NEG_BIG, lst = 0.f;    // per-lane: q = qrow_base + l15

    int ntiles = 2 * jq + 2;
    int cur = 0;
    attn_stage(Kb, Vb, Ks[0], Vs[0], 0, lane, w);
    __syncthreads();                   // vmcnt(0) drain + barrier: tile 0 ready

    #pragma unroll 1
    for (int kt = 0; kt < ntiles; kt++) {
      if (kt + 1 < ntiles)             // async prefetch into other buffer
        attn_stage(Kb, Vb, Ks[cur ^ 1], Vs[cur ^ 1], (kt + 1) * 64, lane, w);

      const __bf16* Kcur = Ks[cur];
      const __bf16* Vcur = Vs[cur];
      floatx4 sc[4];                   // sc[ni][r]: key=ni*16+l4*4+r, q=l15
      #pragma unroll
      for (int ni = 0; ni < 4; ni++) sc[ni] = zf;
      __builtin_amdgcn_s_setprio(1);
      #pragma unroll
      for (int kk = 0; kk < 4; kk++) { // swapped QK^T over D=128
        bf16x8 kf[4];
        #pragma unroll
        for (int ni = 0; ni < 4; ni++) {
          int row = ni * 16 + l15;
          kf[ni] = *(const bf16x8*)(
              &Kcur[row * 128 + (((kk * 4 + l4) ^ (l15 & 7)) << 3)]);
        }
        #pragma unroll
        for (int ni = 0; ni < 4; ni++)
          sc[ni] = __builtin_amdgcn_mfma_f32_16x16x32_bf16(kf[ni], qf[kk], sc[ni], 0, 0, 0);
      }
      __builtin_amdgcn_s_setprio(0);

      if (kt >= 2 * jq) {              // only last two tiles can mask
        int kb = kt * 64 - qb0 - w * 16 - l15;
        #pragma unroll
        for (int ni = 0; ni < 4; ni++)
          #pragma unroll
          for (int r = 0; r < 4; r++)
            if (kb + ni * 16 + l4 * 4 + r > 0) sc[ni][r] = NEG_BIG;
      }

      // row max: in-lane over 16, then across l4 (lanes sharing l15)
      float mt = fmaxf(fmaxf(fmaxf(sc[0][0], sc[0][1]), fmaxf(sc[0][2], sc[0][3])),
                       fmaxf(fmaxf(sc[1][0], sc[1][1]), fmaxf(sc[1][2], sc[1][3])));
      mt = fmaxf(mt,
           fmaxf(fmaxf(fmaxf(sc[2][0], sc[2][1]), fmaxf(sc[2][2], sc[2][3])),
                 fmaxf(fmaxf(sc[3][0], sc[3][1]), fmaxf(sc[3][2], sc[3][3]))));
      mt = fmaxf(mt, __shfl_xor(mt, 16, 64));
      mt = fmaxf(mt, __shfl_xor(mt, 32, 64));

      if (!__all(mt <= mst + 8.0f)) {  // defer-max: rescale only on growth
        float mnew = fmaxf(mst, mt);
        float alpha = exp2f((mst - mnew) * c1);
        mst = mnew;
        lst *= alpha;
        float ar[4];
        #pragma unroll
        for (int r = 0; r < 4; r++)    // alpha for accO row q=l4*4+r lives
          ar[r] = __shfl(alpha, l4 * 20 + r, 64);  // at lane l15=l4*4+r
        #pragma unroll
        for (int nd = 0; nd < 8; nd++)
          #pragma unroll
          for (int r = 0; r < 4; r++) accO[nd][r] *= ar[r];
      }

      float mc = mst * c1;
      float p[4][4];
      float rs = 0.f;
      #pragma unroll
      for (int ni = 0; ni < 4; ni++)
        #pragma unroll
        for (int r = 0; r < 4; r++) {
          p[ni][r] = exp2f(sc[ni][r] * c1 - mc);
          rs += p[ni][r];
        }
      rs += __shfl_xor(rs, 16, 64);
      rs += __shfl_xor(rs, 32, 64);
      lst += rs;

      // pack P -> per-wave LDS: block s=ni*4+l4 (keys 4s..4s+3) at
      // byte l15*128 + ((s>>1)^(l15&7))*16 + (s&1)*8
      #pragma unroll
      for (int ni = 0; ni < 4; ni++) {
        uint2 dw;
        dw.x = cvt_pk_bf16(p[ni][0], p[ni][1]);
        dw.y = cvt_pk_bf16(p[ni][2], p[ni][3]);
        int s = ni * 4 + l4;
        *(uint2*)(&Pw[l15 * 64 + (((s >> 1) ^ (l15 & 7)) << 3) + ((s & 1) << 2)]) = dw;
      }

      __builtin_amdgcn_s_setprio(1);
      #pragma unroll
      for (int kk = 0; kk < 2; kk++) {  // PV: A=P[q][k], B=V^T
        bf16x8 pf = *(const bf16x8*)(
            &Pw[l15 * 64 + (((kk * 4 + l4) ^ (l15 & 7)) << 3)]);
        #pragma unroll
        for (int nd = 0; nd < 8; nd++) {
          int row = nd * 16 + l15;
          bf16x8 vf = *(const bf16x8*)(
              &Vcur[row * 64 + (((kk * 4 + l4) ^ (l15 & 7)) << 3)]);
          accO[nd] = __builtin_amdgcn_mfma_f32_16x16x32_bf16(pf, vf, accO[nd], 0, 0, 0);
        }
      }
      __builtin_amdgcn_s_setprio(0);
      __syncthreads();   // vmcnt(0): prefetch landed; all reads of cur done
      cur ^= 1;
    }

    float invl = 1.0f / lst;
    float ivr[4];
    #pragma unroll
    for (int r = 0; r < 4; r++)
      ivr[r] = __shfl(invl, l4 * 20 + r, 64);   // state lane for q=l4*4+r
    #pragma unroll
    for (int r = 0; r < 4; r++) {
      int srow = qrow_base + l4 * 4 + r;
      size_t rowbase = ((size_t)(b * 2048 + srow)) * 2048 + h * 128;
      #pragma unroll
      for (int nd = 0; nd < 8; nd++)
        Yg[rowbase + nd * 16 + l15] = f2bf(accO[nd][r] * ivr[r]);
    }
  }
}

// ---- GEMM2: out(fp32) = y(bf16) @ w_projT(bf16) + b_proj(fp32)
__global__ __launch_bounds__(256, 3) void gemm_proj(
    const unsigned short* __restrict__ Yin, const unsigned short* __restrict__ WT,
    const float* __restrict__ bias, float* __restrict__ Og) {
  __shared__ unsigned short As[128 * 64];
  __shared__ unsigned short Bs[128 * 64];
  int n0 = blockIdx.x * 128, m0 = blockIdx.y * 128;
  floatx4 acc[4][4];
  gemm_bt_mainloop(Yin, WT, 2048, m0, n0, As, Bs, acc);

  const int t = threadIdx.x, lane = t & 63, w = t >> 6;
  const int wm = w >> 1, wn = w & 1;
  const int l15 = lane & 15, l4 = lane >> 4;
  float bv[4];
  #pragma unroll
  for (int ni = 0; ni < 4; ni++)
    bv[ni] = bias[n0 + wn * 64 + ni * 16 + l15];
  #pragma unroll
  for (int mi = 0; mi < 4; mi++)
    #pragma unroll
    for (int ni = 0; ni < 4; ni++)
      #pragma unroll
      for (int r = 0; r < 4; r++)
        Og[(size_t)(m0 + wm * 64 + mi * 16 + l4 * 4 + r) * 2048 +
           n0 + wn * 64 + ni * 16 + l15] = acc[mi][ni][r] + bv[ni];
}

extern "C" void kernel_launch(void* const* d_in, const int* in_sizes, int n_in,
                              void* d_out, int out_size, void* d_ws, size_t ws_size,
                              hipStream_t stream) {
  const float* x      = (const float*)d_in[0]; // [4,2048,2048] fp32
  const float* w_qkv  = (const float*)d_in[1]; // [2048,6144] fp32
  const float* b_qkv  = (const float*)d_in[2]; // [6144] fp32
  const float* w_proj = (const float*)d_in[3]; // [2048,2048] fp32
  const float* b_proj = (const float*)d_in[4]; // [2048] fp32
  float* out = (float*)d_out;                  // [4,2048,2048] fp32 (64 MiB)
  char* ws = (char*)d_ws;

  // d_out doubles as mid-pipeline scratch (fully overwritten by gemm_proj):
  //   Q bf16 at d_out[0,32M), K bf16 at d_out[32M,64M)
  // ws (88 MiB peak), lifetime-shared:
  //   [0,32M):  Vt bf16 [B,H,D,S]
  //   [32,64M): Xbf bf16 (cvt_x -> gemm_qkv), then Y bf16 (attn -> gemm_proj)
  //   [64,88M): WqT bf16 [6144,2048], later WpT bf16 [2048,2048]
  unsigned short* Q   = (unsigned short*)d_out;
  unsigned short* Kt  = (unsigned short*)((char*)d_out + 33554432);
  unsigned short* Vt  = (unsigned short*)(ws);
  unsigned short* Xbf = (unsigned short*)(ws + 33554432);
  unsigned short* Y   = (unsigned short*)(ws + 33554432);
  unsigned short* WqT = (unsigned short*)(ws + 67108864);
  unsigned short* WpT = (unsigned short*)(ws + 67108864);

  cvt_bf16<<<dim3(8192), 256, 0, stream>>>(x, Xbf);                    // 16M elems
  transpose_cvt<<<dim3(192, 64), 256, 0, stream>>>(w_qkv, WqT, 2048, 6144);
  gemm_qkv<<<dim3(48, 64), 256, 0, stream>>>(Xbf, WqT, b_qkv, Q, Kt, Vt);
  attn<<<dim3(512), 512, 0, stream>>>(Q, Kt, Vt, Y);
  transpose_cvt<<<dim3(64, 64), 256, 0, stream>>>(w_proj, WpT, 2048, 2048);
  gemm_proj<<<dim3(16, 64), 256, 0, stream>>>(Y, WpT, b_proj, out);
}